// Round 5
// baseline (776.975 us; speedup 1.0000x reference)
//
#include <hip/hip_runtime.h>
#include <hip/hip_bf16.h>
#include <stdint.h>

#define N_TOKENS 100000
#define N_ARGS   20000
#define N_EDGES  320000
#define IN_DIM   768
#define HEADS    8
#define OUT_DIM  64
#define ZDIM     512   // HEADS*OUT_DIM

typedef unsigned short u16;
typedef unsigned int   u32;
typedef __bf16 bf16x8 __attribute__((ext_vector_type(8)));
typedef float  f32x4  __attribute__((ext_vector_type(4)));

__device__ __forceinline__ u16 f2bf(float f) {
    union { float f; u32 i; } v; v.f = f;
    u32 u = v.i;
    u += 0x7fffu + ((u >> 16) & 1u);   // RNE
    return (u16)(u >> 16);
}
__device__ __forceinline__ float bf2f(u16 u) {
    union { u32 i; float f; } v; v.i = ((u32)u) << 16; return v.f;
}
__device__ __forceinline__ u32 pk(float lo, float hi) {
    __hip_bfloat162 r = __float22bfloat162_rn(float2{lo, hi});
    union { __hip_bfloat162 b; u32 u; } v; v.b = r; return v.u;
}
__device__ __forceinline__ uint4 pack8(const float4 p, const float4 q) {
    uint4 w;
    w.x = pk(p.x, p.y); w.y = pk(p.z, p.w);
    w.z = pk(q.x, q.y); w.w = pk(q.z, q.w);
    return w;
}

// ---------------------------------------------------------------------------
// GEMM: z[M,512] = h[M,768] @ W[512,768]^T  (fp32 in -> bf16 MFMA, bf16 z,
// fp32 s_node fused from the fp32 accumulator)
// 128x128 tile, BK=32, 256 thr = 4 waves, wave = 4x4 16x16x32 MFMAs.
// ---------------------------------------------------------------------------
__global__ __launch_bounds__(256) void gemm_kernel(
    const float* __restrict__ A,      // h [M, K] fp32
    const float* __restrict__ B,      // W [512, K] fp32
    const float* __restrict__ a_attn, // [128] fp32, use first 64
    u16* __restrict__ z,              // [M, 512] bf16
    float* __restrict__ s_node)       // [M, 8] fp32
{
    __shared__ u16 As[128 * 32];
    __shared__ u16 Bs[128 * 32];

    const int tid  = threadIdx.x;
    const int wave = tid >> 6, lane = tid & 63;
    const int quad = lane >> 4, l16 = lane & 15;
    const int wm = wave >> 1, wn = wave & 1;
    const int bx = blockIdx.x;
    const int tileN = bx & 3;
    const int tileM = bx >> 2;

    // staging: thread t covers tile row t/2, 16 k-elems starting at (t&1)*16
    const int tr = tid >> 1;
    const int tc = (tid & 1) * 16;
    int ga_row = tileM * 128 + tr; if (ga_row >= N_TOKENS) ga_row = N_TOKENS - 1;
    const float* gA = A + (size_t)ga_row * IN_DIM + tc;
    const float* gB = B + (size_t)(tileN * 128 + tr) * IN_DIM + tc;
    u16* sA = As + tid * 16;
    u16* sB = Bs + tid * 16;

    f32x4 acc[4][4];
    const f32x4 zero4 = {0.f, 0.f, 0.f, 0.f};
#pragma unroll
    for (int i = 0; i < 4; i++)
#pragma unroll
        for (int j = 0; j < 4; j++) acc[i][j] = zero4;

    for (int kt = 0; kt < IN_DIM / 32; ++kt) {
        const float4* pa = reinterpret_cast<const float4*>(gA + kt * 32);
        const float4* pb = reinterpret_cast<const float4*>(gB + kt * 32);
        const float4 a0 = pa[0], a1 = pa[1], a2 = pa[2], a3 = pa[3];
        const float4 b0 = pb[0], b1 = pb[1], b2 = pb[2], b3 = pb[3];
        __syncthreads();   // previous iteration's LDS reads complete
        reinterpret_cast<uint4*>(sA)[0] = pack8(a0, a1);
        reinterpret_cast<uint4*>(sA)[1] = pack8(a2, a3);
        reinterpret_cast<uint4*>(sB)[0] = pack8(b0, b1);
        reinterpret_cast<uint4*>(sB)[1] = pack8(b2, b3);
        __syncthreads();   // staging visible to all

        bf16x8 aF[4], bF[4];
#pragma unroll
        for (int i = 0; i < 4; i++)
            aF[i] = *reinterpret_cast<const bf16x8*>(As + (wm * 64 + i * 16 + l16) * 32 + quad * 8);
#pragma unroll
        for (int j = 0; j < 4; j++)
            bF[j] = *reinterpret_cast<const bf16x8*>(Bs + (wn * 64 + j * 16 + l16) * 32 + quad * 8);
#pragma unroll
        for (int i = 0; i < 4; i++)
#pragma unroll
            for (int j = 0; j < 4; j++)
                acc[i][j] = __builtin_amdgcn_mfma_f32_16x16x32_bf16(aF[i], bF[j], acc[i][j], 0, 0, 0);
    }

    // epilogue: store bf16 z; fused s_node = sum_d z*a_src (wave cols = one head)
    float av[4];
#pragma unroll
    for (int j = 0; j < 4; j++) av[j] = a_attn[j * 16 + l16];
    const int head = tileN * 2 + wn;
    const int colb = tileN * 128 + wn * 64;
#pragma unroll
    for (int i = 0; i < 4; i++) {
        const int rowb = tileM * 128 + wm * 64 + i * 16 + quad * 4;
#pragma unroll
        for (int r = 0; r < 4; r++) {
            const int row = rowb + r;
            const bool ok = row < N_TOKENS;
            float p = 0.0f;
#pragma unroll
            for (int j = 0; j < 4; j++) {
                const float v = acc[i][j][r];
                p += v * av[j];
                if (ok) z[(size_t)row * ZDIM + colb + j * 16 + l16] = f2bf(v);
            }
            p += __shfl_xor(p, 1);
            p += __shfl_xor(p, 2);
            p += __shfl_xor(p, 4);
            p += __shfl_xor(p, 8);
            if (ok && l16 == 0) s_node[row * HEADS + head] = p;
        }
    }
}

// ---------------------------------------------------------------------------
// CSR build (bounds-guarded)
// ---------------------------------------------------------------------------
__global__ void zero_kernel(int* __restrict__ p, int n) {
    int i = blockIdx.x * blockDim.x + threadIdx.x;
    if (i < n) p[i] = 0;
}

__global__ void hist_kernel(const int* __restrict__ edst, int* __restrict__ counts) {
    int i = blockIdx.x * blockDim.x + threadIdx.x;
    if (i < N_EDGES) {
        int d = edst[i];
        if ((unsigned)d < (unsigned)N_ARGS) atomicAdd(&counts[d], 1);
    }
}

__global__ void scan_kernel(const int* __restrict__ counts, int* __restrict__ offsets,
                            int* __restrict__ cursor) {
    __shared__ int partial[1024];
    const int tid = threadIdx.x;
    const int C = 20;  // 1024*20 >= 20000
    const int base = tid * C;
    int s = 0;
    for (int k = 0; k < C; k++) { int idx = base + k; if (idx < N_ARGS) s += counts[idx]; }
    partial[tid] = s;
    __syncthreads();
    for (int off = 1; off < 1024; off <<= 1) {
        int v = (tid >= off) ? partial[tid - off] : 0;
        __syncthreads();
        partial[tid] += v;
        __syncthreads();
    }
    int run = (tid == 0) ? 0 : partial[tid - 1];
    for (int k = 0; k < C; k++) {
        int idx = base + k;
        if (idx < N_ARGS) { offsets[idx] = run; cursor[idx] = run; run += counts[idx]; }
    }
    if (tid == 1023) offsets[N_ARGS] = run;
}

__global__ void scatter_kernel(const int* __restrict__ esrc, const int* __restrict__ edst,
                               int* __restrict__ cursor, int* __restrict__ ssrc) {
    int i = blockIdx.x * blockDim.x + threadIdx.x;
    if (i < N_EDGES) {
        int d = edst[i];
        if ((unsigned)d >= (unsigned)N_ARGS) return;
        int s = esrc[i];
        if ((unsigned)s >= (unsigned)N_TOKENS) s = 0;
        int pos = atomicAdd(&cursor[d], 1);
        ssrc[pos] = s;
    }
}

// ---------------------------------------------------------------------------
// Fused per-dst softmax + aggregation: one block per dst arg. OUT IS FP32.
// ---------------------------------------------------------------------------
__global__ __launch_bounds__(256) void agg_kernel(
    const int* __restrict__ offsets, const int* __restrict__ sorted_src,
    const float* __restrict__ s_node, const u16* __restrict__ z,
    float* __restrict__ out)
{
    const int dst = blockIdx.x;
    const int tid = threadIdx.x;
    const int wave = tid >> 6, lane = tid & 63;
    const int start = offsets[dst];
    const int nE = offsets[dst + 1] - start;
    if (nE <= 0) {
        out[(size_t)dst * ZDIM + tid] = 0.0f;
        out[(size_t)dst * ZDIM + tid + 256] = 0.0f;
        return;
    }
    __shared__ float m8[8];
    __shared__ float inv8[8];
    __shared__ float scratch[32];
    __shared__ int   src_lds[64];
    __shared__ float alpha_lds[64 * 8];

    // phase 1: per-head max of leaky_relu(s_node[src])
    float lm[8];
#pragma unroll
    for (int h = 0; h < 8; h++) lm[h] = -1e30f;
    for (int j = tid; j < nE; j += 256) {
        int s = sorted_src[start + j];
        if ((unsigned)s >= (unsigned)N_TOKENS) s = 0;
#pragma unroll
        for (int h = 0; h < 8; h++) {
            float v = s_node[s * 8 + h];
            v = v > 0.0f ? v : 0.01f * v;
            lm[h] = fmaxf(lm[h], v);
        }
    }
#pragma unroll
    for (int off = 1; off < 64; off <<= 1)
#pragma unroll
        for (int h = 0; h < 8; h++) lm[h] = fmaxf(lm[h], __shfl_xor(lm[h], off));
    if (lane == 0) {
#pragma unroll
        for (int h = 0; h < 8; h++) scratch[wave * 8 + h] = lm[h];
    }
    __syncthreads();
    if (tid < 8) {
        float r = scratch[tid];
        for (int w = 1; w < 4; w++) r = fmaxf(r, scratch[w * 8 + tid]);
        m8[tid] = r;
    }
    __syncthreads();

    // phase 2: denom
    float ls[8];
#pragma unroll
    for (int h = 0; h < 8; h++) ls[h] = 0.0f;
    for (int j = tid; j < nE; j += 256) {
        int s = sorted_src[start + j];
        if ((unsigned)s >= (unsigned)N_TOKENS) s = 0;
#pragma unroll
        for (int h = 0; h < 8; h++) {
            float v = s_node[s * 8 + h];
            v = v > 0.0f ? v : 0.01f * v;
            ls[h] += __expf(v - m8[h]);
        }
    }
#pragma unroll
    for (int off = 1; off < 64; off <<= 1)
#pragma unroll
        for (int h = 0; h < 8; h++) ls[h] += __shfl_xor(ls[h], off);
    if (lane == 0) {
#pragma unroll
        for (int h = 0; h < 8; h++) scratch[wave * 8 + h] = ls[h];
    }
    __syncthreads();
    if (tid < 8) {
        float d = scratch[tid];
        for (int w = 1; w < 4; w++) d += scratch[w * 8 + tid];
        if (d == 0.0f) d = 1.0f;
        inv8[tid] = 1.0f / d;
    }
    __syncthreads();

    // phase 3: out[dst] = sum alpha * z[src]; thread owns elems tid and tid+256
    float acc0 = 0.0f, acc1 = 0.0f;
    const int h1 = tid >> 6;
    for (int c0 = 0; c0 < nE; c0 += 64) {
        const int cn = min(64, nE - c0);
        for (int j = tid; j < cn; j += 256) {
            int s = sorted_src[start + c0 + j];
            if ((unsigned)s >= (unsigned)N_TOKENS) s = 0;
            src_lds[j] = s;
        }
        __syncthreads();
        for (int idx = tid; idx < cn * 8; idx += 256) {
            const int j = idx >> 3, h = idx & 7;
            float v = s_node[src_lds[j] * 8 + h];
            v = v > 0.0f ? v : 0.01f * v;
            alpha_lds[idx] = __expf(v - m8[h]) * inv8[h];
        }
        __syncthreads();
        for (int j = 0; j < cn; j++) {
            const int row = src_lds[j];
            acc0 += alpha_lds[j * 8 + h1]     * bf2f(z[(size_t)row * ZDIM + tid]);
            acc1 += alpha_lds[j * 8 + h1 + 4] * bf2f(z[(size_t)row * ZDIM + 256 + tid]);
        }
        __syncthreads();
    }
    out[(size_t)dst * ZDIM + tid] = acc0;
    out[(size_t)dst * ZDIM + 256 + tid] = acc1;
}

// ---------------------------------------------------------------------------
extern "C" void kernel_launch(void* const* d_in, const int* in_sizes, int n_in,
                              void* d_out, int out_size, void* d_ws, size_t ws_size,
                              hipStream_t stream) {
    const float* h      = (const float*)d_in[0];   // fp32 per reference
    const float* W      = (const float*)d_in[1];   // fp32
    const float* a_attn = (const float*)d_in[2];   // fp32
    const int* esrc     = (const int*)d_in[3];
    const int* edst     = (const int*)d_in[4];
    float* out          = (float*)d_out;           // fp32 output (reference dtype)

    char* ws = (char*)d_ws;
    u16*   z        = (u16*)ws;                         // 102,400,000 B
    float* s_node   = (float*)(ws + 102400000);         //   3,200,000 B
    int*   counts   = (int*)(ws + 105600000);           //      80,000 B
    int*   offsets  = (int*)(ws + 105680000);           //      80,016 B
    int*   cursor   = (int*)(ws + 105760016);           //      80,000 B
    int*   ssrc     = (int*)(ws + 105840016);           //   1,280,000 B -> 107.1 MB

    zero_kernel<<<(N_ARGS + 255) / 256, 256, 0, stream>>>(counts, N_ARGS);
    gemm_kernel<<<782 * 4, 256, 0, stream>>>(h, W, a_attn, z, s_node);
    hist_kernel<<<(N_EDGES + 255) / 256, 256, 0, stream>>>(edst, counts);
    scan_kernel<<<1, 1024, 0, stream>>>(counts, offsets, cursor);
    scatter_kernel<<<(N_EDGES + 255) / 256, 256, 0, stream>>>(esrc, edst, cursor, ssrc);
    agg_kernel<<<N_ARGS, 256, 0, stream>>>(offsets, ssrc, s_node, z, out);
}